// Round 2
// baseline (286.842 us; speedup 1.0000x reference)
//
#include <hip/hip_runtime.h>

// GatedEncoderLayer: B=16, I=2048, J=1024, K=1024, F=32
// out[row,k] = sum_f [ (sum_j x[row,j]*Wy[j,f]) * Wx[row%I,f] ] * Wz[k,f]
constexpr int kI = 2048;
constexpr int kJ = 1024;
constexpr int kK = 1024;
constexpr int kF = 32;
constexpr int kRows = 16 * 2048;        // 32768
constexpr int kRowsPerBlk = 16;
constexpr int kThreads = 256;
constexpr int kJSplit = 4;              // j-range split inside block (TLP)
constexpr int kJPer = kJ / kJSplit;     // 256

__global__ __launch_bounds__(kThreads, 4)
void gated_encoder_fused2(const float* __restrict__ x,
                          const float* __restrict__ Wx,
                          const float* __restrict__ Wy,
                          const float* __restrict__ Wz,
                          float* __restrict__ out)
{
    // stage-1 partials: [tid][u], padded to 9 floats -> conflict-free
    __shared__ float red[kThreads][9];            // 9216 B
    // gated t tile: 16 rows x 32 f, stride 36 (16B-aligned rows)
    __shared__ float t2[kRowsPerBlk][kF + 4];     // 2304 B

    const int tid = threadIdx.x;

    // ---------------- stage 1: t[r,f] = sum_j x[row,j]*Wy[j,f] ----------------
    // thread = (r: 16, foct: 4, jq: 4); each sums 256 j's for 8 f's.
    const int r    = tid & 15;
    const int foct = (tid >> 4) & 3;
    const int jq   = tid >> 6;

    const int row = blockIdx.x * kRowsPerBlk + r;
    const int f0  = foct * 8;
    const int j0  = jq * kJPer;

    const float* __restrict__ xrow = x + (size_t)row * kJ + j0;

    float acc[8];
#pragma unroll
    for (int u = 0; u < 8; ++u) acc[u] = 0.0f;

#pragma unroll 2
    for (int j = 0; j < kJPer; j += 8) {
        const float4 xv0 = *reinterpret_cast<const float4*>(xrow + j);
        const float4 xv1 = *reinterpret_cast<const float4*>(xrow + j + 4);
        const float xs[8] = {xv0.x, xv0.y, xv0.z, xv0.w,
                             xv1.x, xv1.y, xv1.z, xv1.w};
#pragma unroll
        for (int u = 0; u < 8; ++u) {
            const float* wyp = Wy + (size_t)(j0 + j + u) * kF + f0;
            const float4 w0 = *reinterpret_cast<const float4*>(wyp);
            const float4 w1 = *reinterpret_cast<const float4*>(wyp + 4);
            acc[0] = fmaf(xs[u], w0.x, acc[0]);
            acc[1] = fmaf(xs[u], w0.y, acc[1]);
            acc[2] = fmaf(xs[u], w0.z, acc[2]);
            acc[3] = fmaf(xs[u], w0.w, acc[3]);
            acc[4] = fmaf(xs[u], w1.x, acc[4]);
            acc[5] = fmaf(xs[u], w1.y, acc[5]);
            acc[6] = fmaf(xs[u], w1.z, acc[6]);
            acc[7] = fmaf(xs[u], w1.w, acc[7]);
        }
    }

#pragma unroll
    for (int u = 0; u < 8; ++u) red[tid][u] = acc[u];
    __syncthreads();

    // ------------- reduce over jq, gate by Wx, stash t2 in LDS -------------
#pragma unroll
    for (int c = 0; c < 2; ++c) {
        const int cell = tid * 2 + c;         // 0..511 = r*32 + f
        const int rr = cell >> 5;
        const int ff = cell & 31;
        const int fo = ff >> 3, uu = ff & 7;
        float s = 0.0f;
#pragma unroll
        for (int q = 0; q < kJSplit; ++q)
            s += red[q * 64 + fo * 16 + rr][uu];
        const int gi = (blockIdx.x * kRowsPerBlk + rr) & (kI - 1);
        t2[rr][ff] = s * Wx[(size_t)gi * kF + ff];
    }
    __syncthreads();

    // ---------------- stage 2: out[r,k] = sum_f t2[r,f]*Wz[k,f] ----------------
    // thread owns 4 contiguous k columns for all 16 rows.
    const int k0 = tid * 4;
    float4 acc2[kRowsPerBlk];
#pragma unroll
    for (int rr = 0; rr < kRowsPerBlk; ++rr)
        acc2[rr] = make_float4(0.f, 0.f, 0.f, 0.f);

#pragma unroll
    for (int fq = 0; fq < 8; ++fq) {
        const float4 z0 = *reinterpret_cast<const float4*>(Wz + (size_t)(k0 + 0) * kF + fq * 4);
        const float4 z1 = *reinterpret_cast<const float4*>(Wz + (size_t)(k0 + 1) * kF + fq * 4);
        const float4 z2 = *reinterpret_cast<const float4*>(Wz + (size_t)(k0 + 2) * kF + fq * 4);
        const float4 z3 = *reinterpret_cast<const float4*>(Wz + (size_t)(k0 + 3) * kF + fq * 4);
#pragma unroll
        for (int rr = 0; rr < kRowsPerBlk; ++rr) {
            const float4 tv = *reinterpret_cast<const float4*>(&t2[rr][fq * 4]);
            acc2[rr].x = fmaf(tv.x, z0.x, fmaf(tv.y, z0.y, fmaf(tv.z, z0.z, fmaf(tv.w, z0.w, acc2[rr].x))));
            acc2[rr].y = fmaf(tv.x, z1.x, fmaf(tv.y, z1.y, fmaf(tv.z, z1.z, fmaf(tv.w, z1.w, acc2[rr].y))));
            acc2[rr].z = fmaf(tv.x, z2.x, fmaf(tv.y, z2.y, fmaf(tv.z, z2.z, fmaf(tv.w, z2.w, acc2[rr].z))));
            acc2[rr].w = fmaf(tv.x, z3.x, fmaf(tv.y, z3.y, fmaf(tv.z, z3.z, fmaf(tv.w, z3.w, acc2[rr].w))));
        }
    }

    const size_t outBase = (size_t)blockIdx.x * kRowsPerBlk * kK;
#pragma unroll
    for (int rr = 0; rr < kRowsPerBlk; ++rr)
        *reinterpret_cast<float4*>(out + outBase + (size_t)rr * kK + k0) = acc2[rr];
}

extern "C" void kernel_launch(void* const* d_in, const int* in_sizes, int n_in,
                              void* d_out, int out_size, void* d_ws, size_t ws_size,
                              hipStream_t stream) {
    const float* x  = (const float*)d_in[0];   // (B, I, J)
    const float* Wx = (const float*)d_in[1];   // (I, F)
    const float* Wy = (const float*)d_in[2];   // (J, F)
    const float* Wz = (const float*)d_in[3];   // (K, F)
    float* out = (float*)d_out;                // (B, I, K) f32

    dim3 grid(kRows / kRowsPerBlk);            // 2048 blocks
    gated_encoder_fused2<<<grid, kThreads, 0, stream>>>(x, Wx, Wy, Wz, out);
}